// Round 1
// baseline (2186.497 us; speedup 1.0000x reference)
//
#include <hip/hip_runtime.h>
#include <math.h>

#define S_ 32
#define V_ 16
#define TH_ 80

__device__ __forceinline__ float silu_f(float x){ return x / (1.f + __expf(-x)); }
__device__ __forceinline__ float sigm_f(float x){ return 1.f / (1.f + __expf(-x)); }

// order-preserving float<->uint for atomicMax
__device__ __forceinline__ unsigned enc_f(float f){
  unsigned u = __float_as_uint(f);
  return (u & 0x80000000u) ? ~u : (u | 0x80000000u);
}
__device__ __forceinline__ float dec_f(unsigned u){
  return (u & 0x80000000u) ? __uint_as_float(u & 0x7fffffffu) : __uint_as_float(~u);
}

__device__ __forceinline__ void fma4(float4& a, float s, const float4 b){
  a.x += s*b.x; a.y += s*b.y; a.z += s*b.z; a.w += s*b.w;
}
__device__ __forceinline__ float4 xor4(float4 a, int m){
  a.x += __shfl_xor(a.x, m);
  a.y += __shfl_xor(a.y, m);
  a.z += __shfl_xor(a.z, m);
  a.w += __shfl_xor(a.w, m);
  return a;
}

// weighted column: acc (init=b2 quad) += sum_h u[h] * W2[h][col quad]
__device__ __forceinline__ float4 wcol(const float* __restrict__ wp,
                                       const float* __restrict__ up,
                                       float4 acc){
  #pragma unroll 4
  for (int h4 = 0; h4 < 16; ++h4){
    float4 u4 = *(const float4*)(up + h4*4);
    const float* w = wp + h4*4*2560;
    float4 w0 = *(const float4*)(w);
    float4 w1 = *(const float4*)(w + 2560);
    float4 w2 = *(const float4*)(w + 5120);
    float4 w3 = *(const float4*)(w + 7680);
    fma4(acc, u4.x, w0); fma4(acc, u4.y, w1);
    fma4(acc, u4.z, w2); fma4(acc, u4.w, w3);
  }
  return acc;
}

__global__ void __launch_bounds__(256) k_init(unsigned* mx, float* den, float* agg, float* bn, int N){
  int t = blockIdx.x*256 + threadIdx.x;
  if (t < N*TH_) agg[t] = 0.f;
  if (t < N){ mx[t] = 0u; den[t] = 0.f; }
  if (t < 80) bn[t] = 0.f;
}

__global__ void __launch_bounds__(256) k_edge(
    const float* __restrict__ nf, const int* __restrict__ ei,
    const float* __restrict__ sh, const float* __restrict__ radial,
    const float* __restrict__ env,
    const float* __restrict__ W1, const float* __restrict__ b1,
    const float* __restrict__ W2, const float* __restrict__ b2,
    const float* __restrict__ Wq, const float* __restrict__ bq,
    const float* __restrict__ Wk, const float* __restrict__ bk,
    float* __restrict__ msgs, float* __restrict__ logits,
    unsigned* __restrict__ mx, int E)
{
  __shared__ float u_lds[32][72];   // stride 72: 16B-aligned rows, conflict-light
  __shared__ float feat[32][81];
  __shared__ float rad[32][17];
  __shared__ int src_l[32], dst_l[32];

  const int t = threadIdx.x;
  const int e0 = blockIdx.x*32;

  if (t < 32){
    int ee = e0 + t;
    src_l[t] = (ee < E) ? ei[ee] : 0;
    dst_l[t] = (ee < E) ? ei[E + ee] : 0;
  }
  __syncthreads();
  for (int i = t; i < 32*16; i += 256){
    int e = i >> 4, r = i & 15;
    int ee = e0 + e;
    rad[e][r] = (ee < E) ? radial[(size_t)ee*16 + r] : 0.f;
  }
  for (int i = t; i < 32*80; i += 256){
    int e = i / 80, idx = i - e*80;
    feat[e][idx] = nf[(size_t)src_l[e]*80 + idx];
  }
  __syncthreads();
  { // u = silu(radial @ W1 + b1), 8 h per thread
    int e = t >> 3, hq = t & 7;
    #pragma unroll
    for (int h8 = 0; h8 < 8; ++h8){
      int h = hq*8 + h8;
      float acc = b1[h];
      #pragma unroll
      for (int r = 0; r < 16; ++r) acc += rad[e][r]*W1[r*64+h];
      u_lds[e][h] = silu_f(acc);
    }
  }
  __syncthreads();

  const int l = t & 63;
  const int kq = l & 7;
  const int es = l >> 3;
  const int wv = t >> 6;
  const int e_loc = wv*8 + es;
  const int e = e0 + e_loc;
  const int kq4 = l & 3;
  const int rh = (l >> 2) & 1;
  const bool act = (e < E);
  const int ec = act ? e : 0;

  const float4 sh4 = *(const float4*)(sh + (size_t)ec*4);
  const float y0 = sh4.x, y1x = sh4.y, y1y = sh4.z, y1z = sh4.w;
  const float inv_s3 = 0.57735026918962576f;
  const float inv_s2 = 0.70710678118654752f;
  const float a0 = 0.14433756729740643f;  // 1/sqrt(48)
  const float a1 = 0.125f;                // 1/sqrt(64)

  const float* up = &u_lds[e_loc][0];
  const float* fr = &feat[e_loc][0];

  // ---- phase A: WA (32x32), cols j = s*32+k
  float4 accA = {0,0,0,0};
  for (int s = 0; s < 32; ++s){
    float4 wa = *(const float4*)(b2 + s*32 + kq*4);
    wa = wcol(W2 + s*32 + kq*4, up, wa);
    fma4(accA, fr[s], wa);
  }
  // ---- phase B: WB (16x32)
  float4 accB = {0,0,0,0};
  for (int v = 0; v < 16; ++v){
    float4 wb = *(const float4*)(b2 + 1024 + v*32 + kq*4);
    wb = wcol(W2 + 1024 + v*32 + kq*4, up, wb);
    float vx = fr[32+v*3+0], vy = fr[32+v*3+1], vz = fr[32+v*3+2];
    float dotv = (vx*y1x + vy*y1y + vz*y1z) * inv_s3;
    fma4(accB, dotv, wb);
  }
  // ---- phase C: WC (32x16), rows split across rh halves
  float4 accC = {0,0,0,0};
  for (int si = 0; si < 16; ++si){
    int s = rh*16 + si;
    float4 wc = *(const float4*)(b2 + 1536 + s*16 + kq4*4);
    wc = wcol(W2 + 1536 + s*16 + kq4*4, up, wc);
    fma4(accC, fr[s], wc);
  }
  accC = xor4(accC, 4);
  // ---- phase D: WD (16x16)
  float4 accD0 = {0,0,0,0}, accD1 = {0,0,0,0}, accD2 = {0,0,0,0};
  for (int vi = 0; vi < 8; ++vi){
    int v = rh*8 + vi;
    float4 wd = *(const float4*)(b2 + 2048 + v*16 + kq4*4);
    wd = wcol(W2 + 2048 + v*16 + kq4*4, up, wd);
    float vx = fr[32+v*3+0], vy = fr[32+v*3+1], vz = fr[32+v*3+2];
    fma4(accD0, vx, wd); fma4(accD1, vy, wd); fma4(accD2, vz, wd);
  }
  accD0 = xor4(accD0, 4); accD1 = xor4(accD1, 4); accD2 = xor4(accD2, 4);
  // ---- phase E: WE (16x16), coef = cross(v_src, y1)/sqrt2
  float4 accE0 = {0,0,0,0}, accE1 = {0,0,0,0}, accE2 = {0,0,0,0};
  for (int vi = 0; vi < 8; ++vi){
    int v = rh*8 + vi;
    float4 we = *(const float4*)(b2 + 2304 + v*16 + kq4*4);
    we = wcol(W2 + 2304 + v*16 + kq4*4, up, we);
    float vx = fr[32+v*3+0], vy = fr[32+v*3+1], vz = fr[32+v*3+2];
    float cx = (vy*y1z - vz*y1y) * inv_s2;
    float cy = (vz*y1x - vx*y1z) * inv_s2;
    float cz = (vx*y1y - vy*y1x) * inv_s2;
    fma4(accE0, cx, we); fma4(accE1, cy, we); fma4(accE2, cz, we);
  }
  accE0 = xor4(accE0, 4); accE1 = xor4(accE1, 4); accE2 = xor4(accE2, 4);

  // assemble messages
  float4 ms;
  ms.x = a0*(y0*accA.x + accB.x);
  ms.y = a0*(y0*accA.y + accB.y);
  ms.z = a0*(y0*accA.z + accB.z);
  ms.w = a0*(y0*accA.w + accB.w);
  float4 mv0, mv1, mv2;
  mv0.x = a1*(y1x*accC.x + y0*accD0.x + accE0.x);
  mv0.y = a1*(y1x*accC.y + y0*accD0.y + accE0.y);
  mv0.z = a1*(y1x*accC.z + y0*accD0.z + accE0.z);
  mv0.w = a1*(y1x*accC.w + y0*accD0.w + accE0.w);
  mv1.x = a1*(y1y*accC.x + y0*accD1.x + accE1.x);
  mv1.y = a1*(y1y*accC.y + y0*accD1.y + accE1.y);
  mv1.z = a1*(y1y*accC.z + y0*accD1.z + accE1.z);
  mv1.w = a1*(y1y*accC.w + y0*accD1.w + accE1.w);
  mv2.x = a1*(y1z*accC.x + y0*accD2.x + accE2.x);
  mv2.y = a1*(y1z*accC.y + y0*accD2.y + accE2.y);
  mv2.z = a1*(y1z*accC.z + y0*accD2.z + accE2.z);
  mv2.w = a1*(y1z*accC.w + y0*accD2.w + accE2.w);

  if (act){
    float* mrow = msgs + (size_t)e*80;
    *(float4*)(mrow + kq*4) = ms;
    if (rh == 0){
      const float* p0 = &mv0.x; const float* p1 = &mv1.x; const float* p2 = &mv2.x;
      #pragma unroll
      for (int i = 0; i < 4; ++i){
        int k = kq4*4 + i;
        mrow[32 + k*3 + 0] = p0[i];
        mrow[32 + k*3 + 1] = p1[i];
        mrow[32 + k*3 + 2] = p2[i];
      }
    }
  }

  // attention logit: q = nf[dst,:32]@Wq+bq ; k = msg_s@Wk+bk
  int dn = dst_l[e_loc];
  float4 qs = *(const float4*)(nf + (size_t)dn*80 + kq*4);
  float pk[8], pq[8];
  #pragma unroll
  for (int j = 0; j < 8; ++j){
    pk[j] = ms.x*Wk[(kq*4+0)*8+j] + ms.y*Wk[(kq*4+1)*8+j]
          + ms.z*Wk[(kq*4+2)*8+j] + ms.w*Wk[(kq*4+3)*8+j];
    pq[j] = qs.x*Wq[(kq*4+0)*8+j] + qs.y*Wq[(kq*4+1)*8+j]
          + qs.z*Wq[(kq*4+2)*8+j] + qs.w*Wq[(kq*4+3)*8+j];
  }
  #pragma unroll
  for (int m = 1; m < 8; m <<= 1){
    #pragma unroll
    for (int j = 0; j < 8; ++j){
      pk[j] += __shfl_xor(pk[j], m);
      pq[j] += __shfl_xor(pq[j], m);
    }
  }
  if (kq == 0 && act){
    float lg = 0.f;
    #pragma unroll
    for (int j = 0; j < 8; ++j) lg += (pq[j]+bq[j])*(pk[j]+bk[j]);
    lg *= 0.35355339059327373f;  // 1/sqrt(8)
    lg += logf(env[e] + 1e-8f);
    logits[e] = lg;
    atomicMax(&mx[dn], enc_f(lg));
  }
}

__global__ void __launch_bounds__(256) k_soft1(const float* __restrict__ logits,
    const int* __restrict__ ei, const unsigned* __restrict__ mx,
    float* __restrict__ den, float* __restrict__ exb, int E){
  int e = blockIdx.x*256 + threadIdx.x;
  if (e >= E) return;
  int d = ei[E + e];
  float ex = __expf(logits[e] - dec_f(mx[d]));
  exb[e] = ex;
  atomicAdd(&den[d], ex);
}

__global__ void __launch_bounds__(256) k_scatter(const float* __restrict__ msgs,
    const float* __restrict__ exb, const float* __restrict__ den,
    const int* __restrict__ ei, float* __restrict__ agg, int E){
  int t = blockIdx.x*256 + threadIdx.x;
  if (t >= E*20) return;
  int e = t/20, r = t - (t/20)*20;
  int d = ei[E + e];
  float attn = exb[e] / (den[d] + 1e-8f);
  float4 m4 = ((const float4*)(msgs + (size_t)e*80))[r];
  float* ap = agg + (size_t)d*80 + r*4;
  atomicAdd(ap+0, attn*m4.x);
  atomicAdd(ap+1, attn*m4.y);
  atomicAdd(ap+2, attn*m4.z);
  atomicAdd(ap+3, attn*m4.w);
}

__global__ void __launch_bounds__(256) k_node(const float* __restrict__ agg,
    const float* __restrict__ nf,
    const float* __restrict__ Wout_s, const float* __restrict__ Wout_v,
    const float* __restrict__ Wg_s, const float* __restrict__ Wg_v,
    float* __restrict__ xbuf, float* __restrict__ bnacc, int N)
{
  __shared__ float t1[4][96];
  __shared__ float t2[4][96];
  __shared__ float bnl[80];
  int t = threadIdx.x, l = t & 63, wv = t >> 6;
  int n = blockIdx.x*4 + wv;
  bool act = (n < N);
  int nc = act ? n : 0;
  if (t < 80) bnl[t] = 0.f;
  __syncthreads();
  const float* arow = agg + (size_t)nc*80;
  const float iS = 0.17677669529663687f;  // 1/sqrt(32)
  const float iV = 0.25f;                 // 1/sqrt(16)
  for (int o = l; o < 80; o += 64){
    float val = 0.f;
    if (o < 32){
      for (int s = 0; s < 32; ++s) val += arow[s]*Wout_s[s*32+o];
      val *= iS;
    } else {
      int w = (o-32)/3, c = (o-32)-w*3;
      for (int v = 0; v < 16; ++v) val += arow[32+v*3+c]*Wout_v[v*16+w];
      val *= iV;
    }
    t1[wv][o] = val;
  }
  __syncthreads();
  for (int o = l; o < 96; o += 64){
    float val = 0.f;
    if (o < 48){
      for (int k = 0; k < 32; ++k) val += t1[wv][k]*Wg_s[k*48+o];
      val *= iS;
    } else {
      int w = (o-48)/3, c = (o-48)-w*3;
      for (int v = 0; v < 16; ++v) val += t1[wv][32+v*3+c]*Wg_v[v*16+w];
      val *= iV;
    }
    t2[wv][o] = val;
  }
  __syncthreads();
  for (int o = l; o < 80; o += 64){
    float x;
    if (o < 32){
      x = silu_f(t2[wv][o]) + nf[(size_t)nc*80+o];
      if (act){
        xbuf[(size_t)n*80+o] = x;
        atomicAdd(&bnl[o], x);
        atomicAdd(&bnl[32+o], x*x);
      }
    } else {
      int w = (o-32)/3;
      x = sigm_f(t2[wv][32+w]) * t2[wv][48+(o-32)] + nf[(size_t)nc*80+o];
      if (act){
        xbuf[(size_t)n*80+o] = x;
        atomicAdd(&bnl[64+w], x*x);
      }
    }
  }
  __syncthreads();
  if (t < 80) atomicAdd(&bnacc[t], bnl[t]);
}

__global__ void k_bn(const float* __restrict__ bnacc,
    const float* __restrict__ bn_ws, const float* __restrict__ bn_bs,
    const float* __restrict__ bn_wv, float* __restrict__ coef, int N){
  int t = threadIdx.x;
  float fN = (float)N;
  if (t < 32){
    float mean = bnacc[t]/fN;
    float var = bnacc[32+t]/fN - mean*mean;
    float cm = bn_ws[t]*rsqrtf(var + 1e-5f);
    coef[t] = cm;
    coef[32+t] = bn_bs[t] - mean*cm;
  } else if (t < 48){
    int v = t - 32;
    float vn = bnacc[64+v]/(3.f*fN);
    coef[64+v] = bn_wv[v]*rsqrtf(vn + 1e-5f);
  }
}

__global__ void __launch_bounds__(256) k_out(const float* __restrict__ xbuf,
    const float* __restrict__ coef, float* __restrict__ out, int N){
  int t = blockIdx.x*256 + threadIdx.x;
  if (t >= N*80) return;
  int n = t/80, o = t - n*80;
  float x = xbuf[t];
  out[t] = (o < 32) ? (x*coef[o] + coef[32+o]) : (x*coef[64+(o-32)/3]);
}

extern "C" void kernel_launch(void* const* d_in, const int* in_sizes, int n_in,
                              void* d_out, int out_size, void* d_ws, size_t ws_size,
                              hipStream_t stream) {
  const float* nf     = (const float*)d_in[0];
  const int*   ei     = (const int*)  d_in[1];
  const float* sh     = (const float*)d_in[2];
  const float* radial = (const float*)d_in[3];
  const float* env    = (const float*)d_in[4];
  const float* W1     = (const float*)d_in[5];
  const float* b1     = (const float*)d_in[6];
  const float* W2     = (const float*)d_in[7];
  const float* b2     = (const float*)d_in[8];
  const float* Wq     = (const float*)d_in[9];
  const float* bq     = (const float*)d_in[10];
  const float* Wk     = (const float*)d_in[11];
  const float* bk     = (const float*)d_in[12];
  const float* Wout_s = (const float*)d_in[13];
  const float* Wout_v = (const float*)d_in[14];
  const float* Wg_s   = (const float*)d_in[15];
  const float* Wg_v   = (const float*)d_in[16];
  const float* bn_ws  = (const float*)d_in[17];
  const float* bn_bs  = (const float*)d_in[18];
  const float* bn_wv  = (const float*)d_in[19];

  const int E = in_sizes[4];
  const int N = in_sizes[0] / 80;

  float* ws = (float*)d_ws;
  size_t off = 0;
  float* msgs   = ws + off; off += (size_t)E*80;
  float* logits = ws + off; off += E;
  float* exb    = ws + off; off += E;
  unsigned* mx  = (unsigned*)(ws + off); off += N;
  float* den    = ws + off; off += N;
  float* agg    = ws + off; off += (size_t)N*80;
  float* xbuf   = ws + off; off += (size_t)N*80;
  float* bnacc  = ws + off; off += 80;
  float* coef   = ws + off; off += 80;

  k_init<<<(N*80 + 255)/256, 256, 0, stream>>>(mx, den, agg, bnacc, N);
  k_edge<<<(E + 31)/32, 256, 0, stream>>>(nf, ei, sh, radial, env,
      W1, b1, W2, b2, Wq, bq, Wk, bk, msgs, logits, mx, E);
  k_soft1<<<(E + 255)/256, 256, 0, stream>>>(logits, ei, mx, den, exb, E);
  k_scatter<<<(E*20 + 255)/256, 256, 0, stream>>>(msgs, exb, den, ei, agg, E);
  k_node<<<(N + 3)/4, 256, 0, stream>>>(agg, nf, Wout_s, Wout_v, Wg_s, Wg_v, xbuf, bnacc, N);
  k_bn<<<1, 64, 0, stream>>>(bnacc, bn_ws, bn_bs, bn_wv, coef, N);
  k_out<<<(N*80 + 255)/256, 256, 0, stream>>>(xbuf, coef, (float*)d_out, N);
}

// Round 2
// 2060.298 us; speedup vs baseline: 1.0613x; 1.0613x over previous
//
#include <hip/hip_runtime.h>
#include <math.h>

#define TH_ 80

__device__ __forceinline__ float silu_f(float x){ return x / (1.f + __expf(-x)); }
__device__ __forceinline__ float sigm_f(float x){ return 1.f / (1.f + __expf(-x)); }

__device__ __forceinline__ unsigned enc_f(float f){
  unsigned u = __float_as_uint(f);
  return (u & 0x80000000u) ? ~u : (u | 0x80000000u);
}
__device__ __forceinline__ float dec_f(unsigned u){
  return (u & 0x80000000u) ? __uint_as_float(u & 0x7fffffffu) : __uint_as_float(~u);
}

__device__ __forceinline__ void fma4(float4& a, float s, const float4 b){
  a.x += s*b.x; a.y += s*b.y; a.z += s*b.z; a.w += s*b.w;
}

__global__ void __launch_bounds__(256) k_init(unsigned* mx, float* den, float* agg, float* bn, int N){
  int t = blockIdx.x*256 + threadIdx.x;
  if (t < N*TH_) agg[t] = 0.f;
  if (t < N){ mx[t] = 0u; den[t] = 0.f; }
  if (t < 80) bn[t] = 0.f;
}

// 8 edges per 256-thread block. W2 is read exactly once per block (no
// per-edge redundancy): lanes = (col-quad x edge), row-ranges split across
// waves; per-row accumulators in registers, coefficient-combine, then LDS
// atomic reduction into the per-edge message accumulator.
__global__ void __launch_bounds__(256) k_edge(
    const float* __restrict__ nf, const int* __restrict__ ei,
    const float* __restrict__ sh, const float* __restrict__ radial,
    const float* __restrict__ env,
    const float* __restrict__ W1, const float* __restrict__ b1,
    const float* __restrict__ W2, const float* __restrict__ b2,
    const float* __restrict__ Wq, const float* __restrict__ bq,
    const float* __restrict__ Wk, const float* __restrict__ bk,
    float* __restrict__ msgs, float* __restrict__ logits,
    unsigned* __restrict__ mx, int E)
{
  __shared__ float u_lds[8][68];   // stride 68: e-groups hit disjoint bank quads
  __shared__ float feat[8][81];
  __shared__ float macc[8][80];    // per-edge message accumulator
  __shared__ float shl[8][4];
  __shared__ float radl[8][17];
  __shared__ int src_l[8], dst_l[8];

  const int t = threadIdx.x;
  const int e0 = blockIdx.x*8;

  // ---- stage 1: indices, sh, radial, zero macc
  if (t < 8){
    int ee = e0 + t; int ec = (ee < E) ? ee : (E-1);
    src_l[t] = ei[ec];
    dst_l[t] = ei[E + ec];
  }
  if (t < 32){
    int e = t >> 2, c = t & 3;
    int ee = e0 + e; int ec = (ee < E) ? ee : (E-1);
    shl[e][c] = sh[(size_t)ec*4 + c];
  }
  for (int i = t; i < 128; i += 256){
    int e = i >> 4, r = i & 15;
    int ee = e0 + e; int ec = (ee < E) ? ee : (E-1);
    radl[e][r] = radial[(size_t)ec*16 + r];
  }
  for (int i = t; i < 640; i += 256) ((float*)macc)[i] = 0.f;
  __syncthreads();

  // ---- stage 2: src features + u = silu(radial@W1+b1)
  for (int i = t; i < 640; i += 256){
    int e = i / 80, idx = i - e*80;
    feat[e][idx] = nf[(size_t)src_l[e]*80 + idx];
  }
  {
    int e = t >> 5, hb = (t & 31)*2;
    #pragma unroll
    for (int hh = 0; hh < 2; ++hh){
      int h = hb + hh;
      float acc = b1[h];
      #pragma unroll
      for (int r = 0; r < 16; ++r) acc += radl[e][r]*W1[r*64+h];
      u_lds[e][h] = silu_f(acc);
    }
  }
  __syncthreads();

  const int l = t & 63;
  const int wv = t >> 6;
  const float inv_s3 = 0.57735026918962576f;
  const float inv_s2 = 0.70710678118654752f;
  const float a0 = 0.14433756729740643f;  // 1/sqrt(48)
  const float a1 = 0.125f;                // 1/sqrt(64)

  // ======== phases A+B: scalar messages (cols 32, lane = kq(8) x e(8)) ====
  {
    const int kq = l & 7;
    const int ea = l >> 3;
    const float y0 = shl[ea][0], y1x = shl[ea][1], y1y = shl[ea][2], y1z = shl[ea][3];
    const float* urow = &u_lds[ea][0];
    float4 mAB = {0,0,0,0};

    // phase A: WA rows s, this thread covers s = wv*8 .. +7
    {
      const int sbase = wv*8;
      float4 a[8];
      #pragma unroll
      for (int s = 0; s < 8; ++s)
        a[s] = *(const float4*)(b2 + (sbase+s)*32 + kq*4);
      for (int h4 = 0; h4 < 16; ++h4){
        float4 u4 = *(const float4*)(urow + h4*4);
        const float* wb = W2 + h4*4*2560 + kq*4;
        #pragma unroll
        for (int s = 0; s < 8; ++s){
          const float* w = wb + (sbase+s)*32;
          float4 w0 = *(const float4*)(w);
          float4 w1 = *(const float4*)(w + 2560);
          float4 w2 = *(const float4*)(w + 5120);
          float4 w3 = *(const float4*)(w + 7680);
          fma4(a[s], u4.x, w0); fma4(a[s], u4.y, w1);
          fma4(a[s], u4.z, w2); fma4(a[s], u4.w, w3);
        }
      }
      #pragma unroll
      for (int s = 0; s < 8; ++s)
        fma4(mAB, a0*y0*feat[ea][sbase+s], a[s]);
    }
    // phase B: WB rows v, this thread covers v = wv*4 .. +3
    {
      const int vbase = wv*4;
      float4 bacc[4];
      #pragma unroll
      for (int v = 0; v < 4; ++v)
        bacc[v] = *(const float4*)(b2 + 1024 + (vbase+v)*32 + kq*4);
      for (int h4 = 0; h4 < 16; ++h4){
        float4 u4 = *(const float4*)(urow + h4*4);
        const float* wb = W2 + 1024 + h4*4*2560 + kq*4;
        #pragma unroll
        for (int v = 0; v < 4; ++v){
          const float* w = wb + (vbase+v)*32;
          float4 w0 = *(const float4*)(w);
          float4 w1 = *(const float4*)(w + 2560);
          float4 w2 = *(const float4*)(w + 5120);
          float4 w3 = *(const float4*)(w + 7680);
          fma4(bacc[v], u4.x, w0); fma4(bacc[v], u4.y, w1);
          fma4(bacc[v], u4.z, w2); fma4(bacc[v], u4.w, w3);
        }
      }
      #pragma unroll
      for (int v = 0; v < 4; ++v){
        int vv = vbase + v;
        float vx = feat[ea][32+vv*3+0], vy = feat[ea][32+vv*3+1], vz = feat[ea][32+vv*3+2];
        float dotv = (vx*y1x + vy*y1y + vz*y1z) * inv_s3;
        fma4(mAB, a0*dotv, bacc[v]);
      }
    }
    atomicAdd(&macc[ea][kq*4+0], mAB.x);
    atomicAdd(&macc[ea][kq*4+1], mAB.y);
    atomicAdd(&macc[ea][kq*4+2], mAB.z);
    atomicAdd(&macc[ea][kq*4+3], mAB.w);
  }

  // ======== phases C+D+E: vector messages (cols 16, lane = kq4(4) x e(8) x half(2))
  {
    const int kq4 = l & 3;
    const int ec = (l >> 2) & 7;
    const int half = l >> 5;
    const float y0 = shl[ec][0], y1x = shl[ec][1], y1y = shl[ec][2], y1z = shl[ec][3];
    const float* urow = &u_lds[ec][0];

    // phase C: WC rows s, covers s = (wv*2+half)*4 .. +3
    float4 cacc[4];
    {
      const int sb = (wv*2 + half)*4;
      #pragma unroll
      for (int s = 0; s < 4; ++s)
        cacc[s] = *(const float4*)(b2 + 1536 + (sb+s)*16 + kq4*4);
      for (int h4 = 0; h4 < 16; ++h4){
        float4 u4 = *(const float4*)(urow + h4*4);
        const float* wb = W2 + 1536 + h4*4*2560 + kq4*4;
        #pragma unroll
        for (int s = 0; s < 4; ++s){
          const float* w = wb + (sb+s)*16;
          float4 w0 = *(const float4*)(w);
          float4 w1 = *(const float4*)(w + 2560);
          float4 w2 = *(const float4*)(w + 5120);
          float4 w3 = *(const float4*)(w + 7680);
          fma4(cacc[s], u4.x, w0); fma4(cacc[s], u4.y, w1);
          fma4(cacc[s], u4.z, w2); fma4(cacc[s], u4.w, w3);
        }
      }
      float4 tC = {0,0,0,0};
      #pragma unroll
      for (int s = 0; s < 4; ++s)
        fma4(tC, a1*feat[ec][sb+s], cacc[s]);
      float tc[4] = {tC.x, tC.y, tC.z, tC.w};
      #pragma unroll
      for (int i = 0; i < 4; ++i){
        int k = kq4*4 + i;
        atomicAdd(&macc[ec][32+k*3+0], y1x*tc[i]);
        atomicAdd(&macc[ec][32+k*3+1], y1y*tc[i]);
        atomicAdd(&macc[ec][32+k*3+2], y1z*tc[i]);
      }
    }
    // phases D+E: WD/WE rows v, covers v = (wv*2+half)*2 .. +1
    {
      const int vb = (wv*2 + half)*2;
      float4 dacc[2], eacc[2];
      #pragma unroll
      for (int v = 0; v < 2; ++v){
        dacc[v] = *(const float4*)(b2 + 2048 + (vb+v)*16 + kq4*4);
        eacc[v] = *(const float4*)(b2 + 2304 + (vb+v)*16 + kq4*4);
      }
      for (int h4 = 0; h4 < 16; ++h4){
        float4 u4 = *(const float4*)(urow + h4*4);
        const float* wbD = W2 + 2048 + h4*4*2560 + kq4*4;
        const float* wbE = W2 + 2304 + h4*4*2560 + kq4*4;
        #pragma unroll
        for (int v = 0; v < 2; ++v){
          const float* wd = wbD + (vb+v)*16;
          float4 d0 = *(const float4*)(wd);
          float4 d1 = *(const float4*)(wd + 2560);
          float4 d2 = *(const float4*)(wd + 5120);
          float4 d3 = *(const float4*)(wd + 7680);
          fma4(dacc[v], u4.x, d0); fma4(dacc[v], u4.y, d1);
          fma4(dacc[v], u4.z, d2); fma4(dacc[v], u4.w, d3);
          const float* we = wbE + (vb+v)*16;
          float4 e0_ = *(const float4*)(we);
          float4 e1 = *(const float4*)(we + 2560);
          float4 e2 = *(const float4*)(we + 5120);
          float4 e3 = *(const float4*)(we + 7680);
          fma4(eacc[v], u4.x, e0_); fma4(eacc[v], u4.y, e1);
          fma4(eacc[v], u4.z, e2); fma4(eacc[v], u4.w, e3);
        }
      }
      float vx[2], vy[2], vz[2], cr0[2], cr1[2], cr2[2];
      #pragma unroll
      for (int v = 0; v < 2; ++v){
        int vv = vb + v;
        vx[v] = feat[ec][32+vv*3+0];
        vy[v] = feat[ec][32+vv*3+1];
        vz[v] = feat[ec][32+vv*3+2];
        cr0[v] = (vy[v]*y1z - vz[v]*y1y) * inv_s2;
        cr1[v] = (vz[v]*y1x - vx[v]*y1z) * inv_s2;
        cr2[v] = (vx[v]*y1y - vy[v]*y1x) * inv_s2;
      }
      #pragma unroll
      for (int cc = 0; cc < 3; ++cc){
        float4 tDE = {0,0,0,0};
        #pragma unroll
        for (int v = 0; v < 2; ++v){
          float vcomp = (cc==0) ? vx[v] : (cc==1) ? vy[v] : vz[v];
          float crc   = (cc==0) ? cr0[v] : (cc==1) ? cr1[v] : cr2[v];
          fma4(tDE, a1*y0*vcomp, dacc[v]);
          fma4(tDE, a1*crc, eacc[v]);
        }
        float td[4] = {tDE.x, tDE.y, tDE.z, tDE.w};
        #pragma unroll
        for (int i = 0; i < 4; ++i){
          int k = kq4*4 + i;
          atomicAdd(&macc[ec][32+k*3+cc], td[i]);
        }
      }
    }
  }
  __syncthreads();

  // ---- logits (wave 0): q.k attention with shuffle reduce over kq
  if (wv == 0){
    const int e = l >> 3;
    const int kq = l & 7;
    const int eg = e0 + e;
    const bool act = (eg < E);
    float4 ms = *(const float4*)&macc[e][kq*4];
    int dn = dst_l[e];
    float4 qs = *(const float4*)(nf + (size_t)dn*80 + kq*4);
    float pk[8], pq[8];
    #pragma unroll
    for (int j = 0; j < 8; ++j){
      pk[j] = ms.x*Wk[(kq*4+0)*8+j] + ms.y*Wk[(kq*4+1)*8+j]
            + ms.z*Wk[(kq*4+2)*8+j] + ms.w*Wk[(kq*4+3)*8+j];
      pq[j] = qs.x*Wq[(kq*4+0)*8+j] + qs.y*Wq[(kq*4+1)*8+j]
            + qs.z*Wq[(kq*4+2)*8+j] + qs.w*Wq[(kq*4+3)*8+j];
    }
    #pragma unroll
    for (int m = 1; m < 8; m <<= 1){
      #pragma unroll
      for (int j = 0; j < 8; ++j){
        pk[j] += __shfl_xor(pk[j], m);
        pq[j] += __shfl_xor(pq[j], m);
      }
    }
    if (kq == 0 && act){
      float lg = 0.f;
      #pragma unroll
      for (int j = 0; j < 8; ++j) lg += (pq[j]+bq[j])*(pk[j]+bk[j]);
      lg *= 0.35355339059327373f;  // 1/sqrt(8)
      lg += logf(env[eg] + 1e-8f);
      logits[eg] = lg;
      atomicMax(&mx[dn], enc_f(lg));
    }
  }

  // ---- store messages
  for (int i = t; i < 160; i += 256){
    int e = i/20, r = i - (i/20)*20;
    if (e0 + e < E)
      ((float4*)(msgs + (size_t)(e0+e)*80))[r] = *(const float4*)&macc[e][r*4];
  }
}

__global__ void __launch_bounds__(256) k_soft1(const float* __restrict__ logits,
    const int* __restrict__ ei, const unsigned* __restrict__ mx,
    float* __restrict__ den, float* __restrict__ exb, int E){
  int e = blockIdx.x*256 + threadIdx.x;
  if (e >= E) return;
  int d = ei[E + e];
  float ex = __expf(logits[e] - dec_f(mx[d]));
  exb[e] = ex;
  atomicAdd(&den[d], ex);
}

__global__ void __launch_bounds__(256) k_scatter(const float* __restrict__ msgs,
    const float* __restrict__ exb, const float* __restrict__ den,
    const int* __restrict__ ei, float* __restrict__ agg, int E){
  int t = blockIdx.x*256 + threadIdx.x;
  if (t >= E*20) return;
  int e = t/20, r = t - (t/20)*20;
  int d = ei[E + e];
  float attn = exb[e] / (den[d] + 1e-8f);
  float4 m4 = ((const float4*)(msgs + (size_t)e*80))[r];
  float* ap = agg + (size_t)d*80 + r*4;
  atomicAdd(ap+0, attn*m4.x);
  atomicAdd(ap+1, attn*m4.y);
  atomicAdd(ap+2, attn*m4.z);
  atomicAdd(ap+3, attn*m4.w);
}

__global__ void __launch_bounds__(256) k_node(const float* __restrict__ agg,
    const float* __restrict__ nf,
    const float* __restrict__ Wout_s, const float* __restrict__ Wout_v,
    const float* __restrict__ Wg_s, const float* __restrict__ Wg_v,
    float* __restrict__ xbuf, float* __restrict__ bnacc, int N)
{
  __shared__ float t1[4][96];
  __shared__ float t2[4][96];
  __shared__ float bnl[80];
  int t = threadIdx.x, l = t & 63, wv = t >> 6;
  int n = blockIdx.x*4 + wv;
  bool act = (n < N);
  int nc = act ? n : 0;
  if (t < 80) bnl[t] = 0.f;
  __syncthreads();
  const float* arow = agg + (size_t)nc*80;
  const float iS = 0.17677669529663687f;  // 1/sqrt(32)
  const float iV = 0.25f;                 // 1/sqrt(16)
  for (int o = l; o < 80; o += 64){
    float val = 0.f;
    if (o < 32){
      for (int s = 0; s < 32; ++s) val += arow[s]*Wout_s[s*32+o];
      val *= iS;
    } else {
      int w = (o-32)/3, c = (o-32)-w*3;
      for (int v = 0; v < 16; ++v) val += arow[32+v*3+c]*Wout_v[v*16+w];
      val *= iV;
    }
    t1[wv][o] = val;
  }
  __syncthreads();
  for (int o = l; o < 96; o += 64){
    float val = 0.f;
    if (o < 48){
      for (int k = 0; k < 32; ++k) val += t1[wv][k]*Wg_s[k*48+o];
      val *= iS;
    } else {
      int w = (o-48)/3, c = (o-48)-w*3;
      for (int v = 0; v < 16; ++v) val += t1[wv][32+v*3+c]*Wg_v[v*16+w];
      val *= iV;
    }
    t2[wv][o] = val;
  }
  __syncthreads();
  for (int o = l; o < 80; o += 64){
    float x;
    if (o < 32){
      x = silu_f(t2[wv][o]) + nf[(size_t)nc*80+o];
      if (act){
        xbuf[(size_t)n*80+o] = x;
        atomicAdd(&bnl[o], x);
        atomicAdd(&bnl[32+o], x*x);
      }
    } else {
      int w = (o-32)/3;
      x = sigm_f(t2[wv][32+w]) * t2[wv][48+(o-32)] + nf[(size_t)nc*80+o];
      if (act){
        xbuf[(size_t)n*80+o] = x;
        atomicAdd(&bnl[64+w], x*x);
      }
    }
  }
  __syncthreads();
  if (t < 80) atomicAdd(&bnacc[t], bnl[t]);
}

__global__ void k_bn(const float* __restrict__ bnacc,
    const float* __restrict__ bn_ws, const float* __restrict__ bn_bs,
    const float* __restrict__ bn_wv, float* __restrict__ coef, int N){
  int t = threadIdx.x;
  float fN = (float)N;
  if (t < 32){
    float mean = bnacc[t]/fN;
    float var = bnacc[32+t]/fN - mean*mean;
    float cm = bn_ws[t]*rsqrtf(var + 1e-5f);
    coef[t] = cm;
    coef[32+t] = bn_bs[t] - mean*cm;
  } else if (t < 48){
    int v = t - 32;
    float vn = bnacc[64+v]/(3.f*fN);
    coef[64+v] = bn_wv[v]*rsqrtf(vn + 1e-5f);
  }
}

__global__ void __launch_bounds__(256) k_out(const float* __restrict__ xbuf,
    const float* __restrict__ coef, float* __restrict__ out, int N){
  int t = blockIdx.x*256 + threadIdx.x;
  if (t >= N*80) return;
  int n = t/80, o = t - n*80;
  float x = xbuf[t];
  out[t] = (o < 32) ? (x*coef[o] + coef[32+o]) : (x*coef[64+(o-32)/3]);
}

extern "C" void kernel_launch(void* const* d_in, const int* in_sizes, int n_in,
                              void* d_out, int out_size, void* d_ws, size_t ws_size,
                              hipStream_t stream) {
  const float* nf     = (const float*)d_in[0];
  const int*   ei     = (const int*)  d_in[1];
  const float* sh     = (const float*)d_in[2];
  const float* radial = (const float*)d_in[3];
  const float* env    = (const float*)d_in[4];
  const float* W1     = (const float*)d_in[5];
  const float* b1     = (const float*)d_in[6];
  const float* W2     = (const float*)d_in[7];
  const float* b2     = (const float*)d_in[8];
  const float* Wq     = (const float*)d_in[9];
  const float* bq     = (const float*)d_in[10];
  const float* Wk     = (const float*)d_in[11];
  const float* bk     = (const float*)d_in[12];
  const float* Wout_s = (const float*)d_in[13];
  const float* Wout_v = (const float*)d_in[14];
  const float* Wg_s   = (const float*)d_in[15];
  const float* Wg_v   = (const float*)d_in[16];
  const float* bn_ws  = (const float*)d_in[17];
  const float* bn_bs  = (const float*)d_in[18];
  const float* bn_wv  = (const float*)d_in[19];

  const int E = in_sizes[4];
  const int N = in_sizes[0] / 80;

  float* ws = (float*)d_ws;
  size_t off = 0;
  float* msgs   = ws + off; off += (size_t)E*80;
  float* logits = ws + off; off += E;
  float* exb    = ws + off; off += E;
  unsigned* mx  = (unsigned*)(ws + off); off += N;
  float* den    = ws + off; off += N;
  float* agg    = ws + off; off += (size_t)N*80;
  float* xbuf   = ws + off; off += (size_t)N*80;
  float* bnacc  = ws + off; off += 80;
  float* coef   = ws + off; off += 80;

  k_init<<<(N*80 + 255)/256, 256, 0, stream>>>(mx, den, agg, bnacc, N);
  k_edge<<<(E + 7)/8, 256, 0, stream>>>(nf, ei, sh, radial, env,
      W1, b1, W2, b2, Wq, bq, Wk, bk, msgs, logits, mx, E);
  k_soft1<<<(E + 255)/256, 256, 0, stream>>>(logits, ei, mx, den, exb, E);
  k_scatter<<<(E*20 + 255)/256, 256, 0, stream>>>(msgs, exb, den, ei, agg, E);
  k_node<<<(N + 3)/4, 256, 0, stream>>>(agg, nf, Wout_s, Wout_v, Wg_s, Wg_v, xbuf, bnacc, N);
  k_bn<<<1, 64, 0, stream>>>(bnacc, bn_ws, bn_bs, bn_wv, coef, N);
  k_out<<<(N*80 + 255)/256, 256, 0, stream>>>(xbuf, coef, (float*)d_out, N);
}